// Round 3
// baseline (613.807 us; speedup 1.0000x reference)
//
#include <hip/hip_runtime.h>
#include <hip/hip_bf16.h>
#include <stdint.h>

typedef short short8 __attribute__((ext_vector_type(8)));
typedef float f32x4  __attribute__((ext_vector_type(4)));

typedef __attribute__((address_space(1))) uint32_t u32_g;
typedef __attribute__((address_space(3))) uint32_t u32_l;

#define BM 256
#define BN 256
// K-tile = 64. LDS: 2 bufs x (A 32KiB + B 32KiB) = 128 KiB.
// buf b at b*65536; A halves at h*16384; B at 32768 + h*16384.

__device__ __forceinline__ void gld_lds16(const void* g, const void* l) {
  __builtin_amdgcn_global_load_lds((u32_g*)(uintptr_t)g, (u32_l*)(uintptr_t)l, 16, 0, 0);
}

// ---------------------------------------------------------------------------
// 8-phase 256x256 GEMM (m201 template): C = epi(A[M,K]bf16 @ BT[N,K]^T + bias)
// 8 waves (2M x 4N), wave tile 128x64, 4 phases per 64-wide K-tile:
//  phi0: ds A-low(8)+B-left(4), stage A(q+1)h0, MFMA i0-3 x j0-1
//  phi1: ds B-right(4),         stage A(q+1)h1, MFMA i0-3 x j2-3
//  phi2: ds A-high(8),          stage B(q+2)h0, MFMA i4-7 x j2-3
//  phi3: (B-left kept in regs), stage B(q+2)h1, vmcnt(4), MFMA i4-7 x j0-1
// Each phase: reads/stage -> barrier -> lgkmcnt(0)+sched_barrier -> prio(1)
// 16 MFMA prio(0) -> barrier.  vmcnt never drained to 0 in steady state.
// ---------------------------------------------------------------------------
template <int FINAL>
__global__ __launch_bounds__(512, 2) void gemm_k(
    const __hip_bfloat16* __restrict__ A,
    const __hip_bfloat16* __restrict__ BT,
    const float* __restrict__ bias,
    __hip_bfloat16* __restrict__ Cb,
    float* __restrict__ Cf,
    const int* __restrict__ tbl,
    int K, int Nreal)
{
  __shared__ __attribute__((aligned(16))) char smem[131072];

  const int tid  = threadIdx.x;
  const int lane = tid & 63;
  const int l15  = lane & 15;
  const int quad = lane >> 4;
  const int wave = tid >> 6;
  const int wm   = (wave >> 2) * 128;   // 2 waves in M
  const int wn   = (wave & 3) * 64;     // 4 waves in N

  const int bm = blockIdx.x * BM;
  const int bn = blockIdx.y * BN;

  // Fragment ds_read offsets. Row r of a 128x64 half: 8 chunks of 16B, chunk c
  // stored at slot (c + r) & 7  -> 16 lanes/quad spread over 8 slots = 2-way.
  // r mod 8 == l15 mod 8 for all frags, so the slot term is per-thread const.
  const uint32_t aB  = (uint32_t)(wm >> 7) * 16384u + (uint32_t)l15 * 128u;
  const uint32_t bB  = 32768u + (uint32_t)(wn >> 7) * 16384u
                     + (uint32_t)((wn & 127) + l15) * 128u;
  const uint32_t cs0 = (uint32_t)((quad + l15) & 7) * 16u;       // kstep 0
  const uint32_t cs1 = (uint32_t)((quad + l15 + 4) & 7) * 16u;   // kstep 1

  // Staging: half-tile = 128 rows x 64 k x 2B = 16 KiB = 2 insts x 512 thr x 16B.
  // LDS dest linear idx*16; global chunk pre-inverse-swizzled: gc = (ch-row)&7.
  const int r0  = tid >> 3,          r1  = (tid + 512) >> 3;
  const int gc0 = ((tid & 7) - r0) & 7, gc1 = (((tid + 512) & 7) - r1) & 7;
  const __hip_bfloat16* aP0 = A  + (size_t)(bm + r0) * K + gc0 * 8;
  const __hip_bfloat16* aP1 = A  + (size_t)(bm + r1) * K + gc1 * 8;
  const __hip_bfloat16* bP0 = BT + (size_t)(bn + r0) * K + gc0 * 8;
  const __hip_bfloat16* bP1 = BT + (size_t)(bn + r1) * K + gc1 * 8;
  const uint32_t dst0 = (uint32_t)tid * 16u;
  const uint32_t dst1 = dst0 + 8192u;
  const size_t   hK   = (size_t)128 * K;

  auto stgA = [&](int q, int h) {
    char*  d  = smem + (q & 1) * 65536 + h * 16384;
    size_t ko = (size_t)q * 64 + (size_t)h * hK;
    gld_lds16(aP0 + ko, d + dst0);
    gld_lds16(aP1 + ko, d + dst1);
  };
  auto stgB = [&](int q, int h) {
    char*  d  = smem + (q & 1) * 65536 + 32768 + h * 16384;
    size_t ko = (size_t)q * 64 + (size_t)h * hK;
    gld_lds16(bP0 + ko, d + dst0);
    gld_lds16(bP1 + ko, d + dst1);
  };

  f32x4 acc[8][4];
#pragma unroll
  for (int i = 0; i < 8; ++i)
#pragma unroll
    for (int j = 0; j < 4; ++j)
      acc[i][j] = (f32x4){0.f, 0.f, 0.f, 0.f};

  const int NQ = K >> 6;

  // Prologue: B(0), A(0), B(1) staged (12 loads); retire first 8 (tile 0).
  stgB(0, 0); stgB(0, 1); stgA(0, 0); stgA(0, 1); stgB(1, 0); stgB(1, 1);
  asm volatile("s_waitcnt vmcnt(4)" ::: "memory");
  __builtin_amdgcn_s_barrier();

  for (int q = 0; q < NQ; ++q) {
    const char* rb = smem + (q & 1) * 65536;
    short8 a0[2][4], a1[2][4], bl[2][2], br[2][2];

    // ---- phi0 ----
#pragma unroll
    for (int s = 0; s < 2; ++s) {
      const uint32_t cs = s ? cs1 : cs0;
#pragma unroll
      for (int i = 0; i < 4; ++i) a0[s][i] = *(const short8*)(rb + aB + i * 2048 + cs);
#pragma unroll
      for (int j = 0; j < 2; ++j) bl[s][j] = *(const short8*)(rb + bB + j * 2048 + cs);
    }
    if (q + 1 < NQ) stgA(q + 1, 0);
    asm volatile("s_waitcnt lgkmcnt(8)" ::: "memory");   // early partial drain
    __builtin_amdgcn_s_barrier();
    asm volatile("s_waitcnt lgkmcnt(0)" ::: "memory");
    __builtin_amdgcn_sched_barrier(0);
    __builtin_amdgcn_s_setprio(1);
#pragma unroll
    for (int s = 0; s < 2; ++s)
#pragma unroll
      for (int i = 0; i < 4; ++i)
#pragma unroll
        for (int j = 0; j < 2; ++j)
          acc[i][j] = __builtin_amdgcn_mfma_f32_16x16x32_bf16(a0[s][i], bl[s][j], acc[i][j], 0, 0, 0);
    __builtin_amdgcn_s_setprio(0);
    __builtin_amdgcn_s_barrier();

    // ---- phi1 ----
#pragma unroll
    for (int s = 0; s < 2; ++s) {
      const uint32_t cs = s ? cs1 : cs0;
#pragma unroll
      for (int j = 0; j < 2; ++j) br[s][j] = *(const short8*)(rb + bB + (j + 2) * 2048 + cs);
    }
    if (q + 1 < NQ) stgA(q + 1, 1);
    __builtin_amdgcn_s_barrier();
    asm volatile("s_waitcnt lgkmcnt(0)" ::: "memory");
    __builtin_amdgcn_sched_barrier(0);
    __builtin_amdgcn_s_setprio(1);
#pragma unroll
    for (int s = 0; s < 2; ++s)
#pragma unroll
      for (int i = 0; i < 4; ++i)
#pragma unroll
        for (int j = 0; j < 2; ++j)
          acc[i][j + 2] = __builtin_amdgcn_mfma_f32_16x16x32_bf16(a0[s][i], br[s][j], acc[i][j + 2], 0, 0, 0);
    __builtin_amdgcn_s_setprio(0);
    __builtin_amdgcn_s_barrier();

    // ---- phi2 ----
#pragma unroll
    for (int s = 0; s < 2; ++s) {
      const uint32_t cs = s ? cs1 : cs0;
#pragma unroll
      for (int i = 0; i < 4; ++i) a1[s][i] = *(const short8*)(rb + aB + (i + 4) * 2048 + cs);
    }
    if (q + 2 < NQ) stgB(q + 2, 0);
    __builtin_amdgcn_s_barrier();
    asm volatile("s_waitcnt lgkmcnt(0)" ::: "memory");
    __builtin_amdgcn_sched_barrier(0);
    __builtin_amdgcn_s_setprio(1);
#pragma unroll
    for (int s = 0; s < 2; ++s)
#pragma unroll
      for (int i = 0; i < 4; ++i)
#pragma unroll
        for (int j = 0; j < 2; ++j)
          acc[i + 4][j + 2] = __builtin_amdgcn_mfma_f32_16x16x32_bf16(a1[s][i], br[s][j], acc[i + 4][j + 2], 0, 0, 0);
    __builtin_amdgcn_s_setprio(0);
    __builtin_amdgcn_s_barrier();

    // ---- phi3 ---- (B-left reused from registers; one counted vmcnt/K-tile)
    if (q + 2 < NQ) stgB(q + 2, 1);
    if (q < NQ - 2)       asm volatile("s_waitcnt vmcnt(4)" ::: "memory");
    else if (q == NQ - 2) asm volatile("s_waitcnt vmcnt(0)" ::: "memory");
    __builtin_amdgcn_s_barrier();
    __builtin_amdgcn_sched_barrier(0);
    __builtin_amdgcn_s_setprio(1);
#pragma unroll
    for (int s = 0; s < 2; ++s)
#pragma unroll
      for (int i = 0; i < 4; ++i)
#pragma unroll
        for (int j = 0; j < 2; ++j)
          acc[i + 4][j] = __builtin_amdgcn_mfma_f32_16x16x32_bf16(a1[s][i], bl[s][j], acc[i + 4][j], 0, 0, 0);
    __builtin_amdgcn_s_setprio(0);
    __builtin_amdgcn_s_barrier();
  }

  // Epilogue. C/D layout: col = lane&15, row = quad*4 + reg (m89-verified).
  if (FINAL == 0) {
#pragma unroll
    for (int j = 0; j < 4; ++j) {
      int   n  = bn + wn + j * 16 + l15;
      float bv = bias[n];
#pragma unroll
      for (int i = 0; i < 8; ++i) {
        int m0 = bm + wm + i * 16 + quad * 4;
#pragma unroll
        for (int r = 0; r < 4; ++r) {
          float v = acc[i][j][r] + bv;
          v = (v > 0.f) ? v : 0.01f * v;
          Cb[(size_t)(m0 + r) * 2048 + n] = __float2bfloat16(v);
        }
      }
    }
  } else {
#pragma unroll
    for (int j = 0; j < 4; ++j) {
      int n = bn + wn + j * 16 + l15;
      if (n < Nreal) {
        float bv   = bias[n];
        int  code  = tbl[n];
        int  dst   = code & 4095;          // r*64 + c (upper triangle)
        bool diag  = (code & 4096) != 0;
        int  mir   = ((dst & 63) << 6) | (dst >> 6);  // (c,r) lower mirror
        const f32x4 z = (f32x4){0.f, 0.f, 0.f, 0.f};
#pragma unroll
        for (int i = 0; i < 8; ++i) {
          int m0 = bm + wm + i * 16 + quad * 4;
          f32x4 pk;
#pragma unroll
          for (int r = 0; r < 4; ++r) {
            float v = acc[i][j][r] + bv;
            if (diag) v = fabsf(v);
            pk[r] = v;
          }
          *reinterpret_cast<f32x4*>(Cf + (size_t)dst * 8192 + m0) = pk;
          if (!diag)  // strict-upper (r,c) <-> strict-lower (c,r) bijection
            *reinterpret_cast<f32x4*>(Cf + (size_t)mir * 8192 + m0) = z;
        }
      }
    }
  }
}

// ---------------------------------------------------------------------------
// Weight transpose + fp32->bf16: in[K,N](f32) -> out[NP,K](bf16), rows >= N zero
// ---------------------------------------------------------------------------
__global__ void transpose_k(const float* __restrict__ in,
                            __hip_bfloat16* __restrict__ out,
                            int K, int N)
{
  __shared__ __hip_bfloat16 t[32][33];
  const int n0 = blockIdx.x * 32;
  const int k0 = blockIdx.y * 32;
  const int tx = threadIdx.x, ty = threadIdx.y;
  const __hip_bfloat16 zero = __float2bfloat16(0.f);
#pragma unroll
  for (int r = 0; r < 32; r += 8) {
    int k = k0 + ty + r, n = n0 + tx;
    t[ty + r][tx] = (n < N) ? __float2bfloat16(in[(size_t)k * N + n]) : zero;
  }
  __syncthreads();
#pragma unroll
  for (int r = 0; r < 32; r += 8) {
    int n = n0 + ty + r;
    out[(size_t)n * K + k0 + tx] = t[tx][ty + r];
  }
}

// fp32 -> bf16 elementwise (x), 4 per thread
__global__ void cvt_k(const float* __restrict__ in,
                      __hip_bfloat16* __restrict__ out, int n)
{
  int i = (blockIdx.x * 256 + threadIdx.x) * 4;
  if (i >= n) return;
  float4 v = *reinterpret_cast<const float4*>(in + i);
  union { unsigned short us[4]; uint2 v2; } pk;
  __hip_bfloat16 h;
  h = __float2bfloat16(v.x); pk.us[0] = *reinterpret_cast<unsigned short*>(&h);
  h = __float2bfloat16(v.y); pk.us[1] = *reinterpret_cast<unsigned short*>(&h);
  h = __float2bfloat16(v.z); pk.us[2] = *reinterpret_cast<unsigned short*>(&h);
  h = __float2bfloat16(v.w); pk.us[3] = *reinterpret_cast<unsigned short*>(&h);
  *reinterpret_cast<uint2*>(out + i) = pk.v2;
}

// l -> (r,c) scatter table. Row r covers cols 63..r; diag (c==r) flagged bit 12.
__global__ void table_k(int* __restrict__ tbl)
{
  int l = blockIdx.x * 64 + threadIdx.x;
  if (l >= 2080) return;
  int r = 0, s = 0;
  while (s + (64 - r) <= l) { s += 64 - r; ++r; }
  int c = 63 - (l - s);
  tbl[l] = (r * 64 + c) | ((r == c) ? 4096 : 0);
}

extern "C" void kernel_launch(void* const* d_in, const int* in_sizes, int n_in,
                              void* d_out, int out_size, void* d_ws, size_t ws_size,
                              hipStream_t stream)
{
  const float* x   = (const float*)d_in[0];
  const float* W1  = (const float*)d_in[1];
  const float* b1  = (const float*)d_in[2];
  const float* W2  = (const float*)d_in[3];
  const float* b2  = (const float*)d_in[4];
  const float* W21 = (const float*)d_in[5];
  const float* b21 = (const float*)d_in[6];
  const float* W22 = (const float*)d_in[7];
  const float* b22 = (const float*)d_in[8];
  const float* W3  = (const float*)d_in[9];
  const float* b3  = (const float*)d_in[10];
  float* out = (float*)d_out;

  char* ws = (char*)d_ws;
  __hip_bfloat16* act0 = (__hip_bfloat16*)(ws);                         // 8192x2048 bf16
  __hip_bfloat16* act1 = (__hip_bfloat16*)(ws + ((size_t)32 << 20));    // 8192x2048 bf16
  __hip_bfloat16* xb   = act1;                                          // 8192x1024 bf16 (dead after GEMM1)
  __hip_bfloat16* W1T  = (__hip_bfloat16*)(ws + ((size_t)64 << 20));    // 2048x1024
  __hip_bfloat16* W2T  = (__hip_bfloat16*)(ws + ((size_t)68 << 20));    // 2048x2048
  __hip_bfloat16* W21T = (__hip_bfloat16*)(ws + ((size_t)76 << 20));    // 2048x2048
  __hip_bfloat16* W22T = (__hip_bfloat16*)(ws + ((size_t)84 << 20));    // 2048x2048
  __hip_bfloat16* W3T  = (__hip_bfloat16*)(ws + ((size_t)92 << 20));    // 2304x2048 zero-padded
  int*            tbl  = (int*)(ws + ((size_t)101 << 20));              // 2080 ints

  // No output memset: FINAL gemm writes upper triangle + mirrored zeros.
  table_k<<<33, 64, 0, stream>>>(tbl);

  cvt_k<<<8192, 256, 0, stream>>>(x, xb, 8192 * 1024);

  dim3 tb(32, 8);
  transpose_k<<<dim3(64, 32), tb, 0, stream>>>(W1,  W1T,  1024, 2048);
  transpose_k<<<dim3(64, 64), tb, 0, stream>>>(W2,  W2T,  2048, 2048);
  transpose_k<<<dim3(64, 64), tb, 0, stream>>>(W21, W21T, 2048, 2048);
  transpose_k<<<dim3(64, 64), tb, 0, stream>>>(W22, W22T, 2048, 2048);
  transpose_k<<<dim3(72, 64), tb, 0, stream>>>(W3,  W3T,  2048, 2080); // rows 2080..2303 zero

  gemm_k<0><<<dim3(32, 8), 512, 0, stream>>>(xb,   W1T,  b1,  act0, nullptr, nullptr, 1024, 2048);
  gemm_k<0><<<dim3(32, 8), 512, 0, stream>>>(act0, W2T,  b2,  act1, nullptr, nullptr, 2048, 2048);
  gemm_k<0><<<dim3(32, 8), 512, 0, stream>>>(act1, W21T, b21, act0, nullptr, nullptr, 2048, 2048);
  gemm_k<0><<<dim3(32, 8), 512, 0, stream>>>(act0, W22T, b22, act1, nullptr, nullptr, 2048, 2048);
  gemm_k<1><<<dim3(32, 9), 512, 0, stream>>>(act1, W3T,  b3,  nullptr, out,  tbl,     2048, 2080);
}